// Round 12
// baseline (429.356 us; speedup 1.0000x reference)
//
#include <hip/hip_runtime.h>
#include <math.h>

// Problem constants (fixed shapes from setup_inputs)
constexpr int B_  = 4;
constexpr int H_  = 64;
constexpr int W_  = 64;
constexpr int C_  = 96;
constexpr int L_  = H_ * W_;        // 4096
constexpr int DI  = 192;            // 2*C
constexpr int K_  = 4;
constexpr int NST = 16;
constexpr int R_  = 6;
constexpr int M_  = B_ * L_;        // 16384 rows

// chunked-scan params
constexpr int NCH = 128;            // number of chunks along L
constexpr int CL  = 32;             // chunk length (NCH*CL == L_)
constexpr int DG  = 12;             // flat partitions of DI*NST/256 in carry kernel

// KAN GEMM params
constexpr int KANK = 864;           // 96 silu + 96*8 spline features
constexpr int KLAY = 96 * KANK;     // 82944 weights per layer

typedef __attribute__((ext_vector_type(8))) short short8;
typedef __attribute__((ext_vector_type(4))) float floatx4;
typedef __attribute__((ext_vector_type(4))) unsigned short ushort4v;

// ---------------- helpers ----------------
__device__ __forceinline__ float wave_sum64(float v) {
#pragma unroll
  for (int off = 1; off < 64; off <<= 1) v += __shfl_xor(v, off, 64);
  return v;
}

__device__ __forceinline__ float exp2_hw(float x) {
  return __builtin_amdgcn_exp2f(x);   // v_exp_f32 (2^x), no mul
}

// spatial position read/written by direction k at scan step l
__device__ __forceinline__ int pos_kl(int k, int l) {
  int ll = (k >= 2) ? (L_ - 1 - l) : l;
  int i = ll & 63;      // row
  int j = ll >> 6;      // diag index
  int col = ((k & 1) == 0) ? ((i + j) & 63) : ((j - i) & 63);
  return (i << 6) + col;
}

// position for pair pr at position-index ll (same for both k of the pair)
__device__ __forceinline__ int pos_pair(int pr, int ll) {
  int i = ll & 63, j = ll >> 6;
  int col = (pr == 0) ? ((i + j) & 63) : ((j - i) & 63);
  return (i << 6) + col;
}

__device__ __forceinline__ float silu_f(float x) {
  return x / (1.f + __expf(-x));
}

// fast softplus: __logf is hw v_log_f32, arg in (1,2] -> ~1ulp
__device__ __forceinline__ float softplus_fast(float s) {
  return fmaxf(s, 0.f) + __logf(1.f + __expf(-fabsf(s)));
}

__device__ __forceinline__ unsigned short f2bf(float f) {
  unsigned u = __float_as_uint(f);
  unsigned r = (u + 0x7FFFu + ((u >> 16) & 1u)) >> 16;
  return (unsigned short)r;
}

__device__ __forceinline__ float bf2f(unsigned short h) {
  return __uint_as_float(((unsigned)h) << 16);
}

// compute the 8 cubic B-spline bases for scalar x (grid g_i = 0.4i - 2.2)
__device__ __forceinline__ void spline8(float x, float* bb /*len 11*/) {
#pragma unroll
  for (int i2 = 0; i2 < 11; i2++) {
    float g0 = 0.4f * i2 - 2.2f;
    float g1 = 0.4f * i2 - 1.8f;
    bb[i2] = (x >= g0 && x < g1) ? 1.f : 0.f;
  }
#pragma unroll
  for (int k2 = 1; k2 <= 3; k2++) {
    float invd = 1.f / (0.4f * k2);
#pragma unroll
    for (int i2 = 0; i2 + k2 < 11; i2++) {
      float gi   = 0.4f * i2 - 2.2f;
      float gik1 = 0.4f * (i2 + k2 + 1) - 2.2f;
      bb[i2] = (x - gi) * invd * bb[i2] + (gik1 - x) * invd * bb[i2 + 1];
    }
  }
}

// ---------------- LN over C=96, one wave per row ----------------
__global__ __launch_bounds__(256) void ln96_kernel(const float* __restrict__ in,
    const float* __restrict__ g, const float* __restrict__ b,
    float* __restrict__ out) {
  int wave = blockIdx.x * 4 + (threadIdx.x >> 6);
  int lane = threadIdx.x & 63;
  const float* rp = in + (size_t)wave * C_;
  float v0 = rp[lane];
  float v1 = (lane < C_ - 64) ? rp[lane + 64] : 0.f;
  float s  = wave_sum64(v0 + v1);
  float s2 = wave_sum64(v0 * v0 + v1 * v1);
  float mean = s * (1.f / C_);
  float var  = s2 * (1.f / C_) - mean * mean;
  float inv  = rsqrtf(var + 1e-5f);
  float* op = out + (size_t)wave * C_;
  op[lane] = (v0 - mean) * inv * g[lane] + b[lane];
  if (lane < C_ - 64) op[lane + 64] = (v1 - mean) * inv * g[lane + 64] + b[lane + 64];
}

// ---------------- pack in_proj_w into hi/lo bf16 (once per launch) ----------------
__global__ __launch_bounds__(256) void prep_inproj_kernel(const float* __restrict__ w,
    unsigned short* __restrict__ wio) {
  int idx = blockIdx.x * 256 + threadIdx.x;  // 384*96 = 36864
  if (idx >= 384 * 96) return;
  float v = w[idx];
  unsigned short hh = f2bf(v);
  wio[idx] = hh;
  wio[36864 + idx] = f2bf(v - bf2f(hh));
}

// ---------------- pack out_proj_w (96x192) into hi/lo bf16 ----------------
__global__ __launch_bounds__(256) void prep_outproj_kernel(const float* __restrict__ w,
    unsigned short* __restrict__ wo) {
  int idx = blockIdx.x * 256 + threadIdx.x;  // 96*192 = 18432
  if (idx >= 96 * 192) return;
  float v = w[idx];
  unsigned short hh = f2bf(v);
  wo[idx] = hh;
  wo[18432 + idx] = f2bf(v - bf2f(hh));
}

// ---------------- A2 table: -exp(A_logs)*log2(e), [K*DI][NST] ----------------
__global__ __launch_bounds__(256) void prep_a2_kernel(const float* __restrict__ A_logs,
    float* __restrict__ a2g) {
  int idx = blockIdx.x * 256 + threadIdx.x;  // K*DI*NST = 12288
  if (idx < K_ * DI * NST) a2g[idx] = -__expf(A_logs[idx]) * 1.44269504f;
}

// ---------------- in_proj via bf16 hi/lo MFMA ----------------
// grid: (M/64)*2 blocks; block handles 64 rows x 2 N-chunks of 96
__global__ __launch_bounds__(256) void gemm_in_mfma_kernel(const float* __restrict__ h,
    const unsigned short* __restrict__ wio, float* __restrict__ xin,
    float* __restrict__ z) {
  __shared__ __align__(16) unsigned short Wh[96][104];
  __shared__ __align__(16) unsigned short Wl[96][104];
  int row0 = (blockIdx.x >> 1) * 64;
  int nc0  = (blockIdx.x & 1) * 2;
  int tid = threadIdx.x;
  int wv = tid >> 6, lane = tid & 63, mrow = lane & 15, quad = lane >> 4;

  short8 ah[3], al[3];
  const float* hr = h + (size_t)(row0 + wv * 16 + mrow) * C_;
#pragma unroll
  for (int ks = 0; ks < 3; ks++) {
    float4 va = *(const float4*)&hr[ks * 32 + quad * 8];
    float4 vb = *(const float4*)&hr[ks * 32 + quad * 8 + 4];
    float f[8] = {va.x, va.y, va.z, va.w, vb.x, vb.y, vb.z, vb.w};
    short8 hh, ll;
#pragma unroll
    for (int q = 0; q < 8; q++) {
      unsigned short hv = f2bf(f[q]);
      hh[q] = (short)hv;
      ll[q] = (short)f2bf(f[q] - bf2f(hv));
    }
    ah[ks] = hh; al[ks] = ll;
  }
  for (int nci = 0; nci < 2; nci++) {       // 2 chunks of 96 output cols
    int nc = nc0 + nci;
    if (nci) __syncthreads();
    for (int t = tid; t < 96 * 12; t += 256) {
      int j = t / 12, u = t % 12;
      *(short8*)&Wh[j][u * 8] = *(const short8*)&wio[(size_t)(nc * 96 + j) * 96 + u * 8];
      *(short8*)&Wl[j][u * 8] = *(const short8*)&wio[(size_t)(384 + nc * 96 + j) * 96 + u * 8];
    }
    __syncthreads();
    floatx4 acc[6];
#pragma unroll
    for (int q = 0; q < 6; q++) acc[q] = (floatx4)(0.f);
#pragma unroll
    for (int ks = 0; ks < 3; ks++) {
#pragma unroll
      for (int nt = 0; nt < 6; nt++) {
        short8 bh = *(const short8*)&Wh[nt * 16 + mrow][ks * 32 + quad * 8];
        short8 bl = *(const short8*)&Wl[nt * 16 + mrow][ks * 32 + quad * 8];
        acc[nt] = __builtin_amdgcn_mfma_f32_16x16x32_bf16(ah[ks], bh, acc[nt], 0, 0, 0);
        acc[nt] = __builtin_amdgcn_mfma_f32_16x16x32_bf16(al[ks], bh, acc[nt], 0, 0, 0);
        acc[nt] = __builtin_amdgcn_mfma_f32_16x16x32_bf16(ah[ks], bl, acc[nt], 0, 0, 0);
      }
    }
#pragma unroll
    for (int nt = 0; nt < 6; nt++) {
      int j = nc * 96 + nt * 16 + mrow;
#pragma unroll
      for (int rg = 0; rg < 4; rg++) {
        int row = row0 + wv * 16 + quad * 4 + rg;
        float v = acc[nt][rg];
        if (j < DI) xin[(size_t)row * DI + j] = v;
        else        z[(size_t)row * DI + (j - DI)] = v;
      }
    }
  }
}

// ---------------- depthwise 3x3 conv (NHWC) + SiLU, 2 pixels/block ----------------
__global__ __launch_bounds__(192) void conv_silu_kernel(const float* __restrict__ xin,
    const float* __restrict__ cw, const float* __restrict__ cb, float* __restrict__ imgT) {
  int p0 = blockIdx.x * 2;
  int b = p0 >> 12;
  int ij = p0 & 4095;
  int i = ij >> 6, j0 = ij & 63;   // j0 even, j0+1 <= 63
  int c = threadIdx.x;
  float v[3][4];
#pragma unroll
  for (int r = 0; r < 3; r++) {
    int ii = i - 1 + r;
    bool rok = (ii >= 0 && ii < H_);
#pragma unroll
    for (int cc = 0; cc < 4; cc++) {
      int jj = j0 - 1 + cc;
      v[r][cc] = (rok && jj >= 0 && jj < W_)
                     ? xin[((size_t)b * L_ + ii * W_ + jj) * DI + c] : 0.f;
    }
  }
  const float* wc = cw + c * 9;
  float w[9];
#pragma unroll
  for (int q = 0; q < 9; q++) w[q] = wc[q];
  float a0 = cb[c], a1 = a0;
#pragma unroll
  for (int r = 0; r < 3; r++) {
#pragma unroll
    for (int t = 0; t < 3; t++) {
      a0 += v[r][t]     * w[r * 3 + t];
      a1 += v[r][t + 1] * w[r * 3 + t];
    }
  }
  imgT[(size_t)p0 * DI + c]       = silu_f(a0);
  imgT[(size_t)(p0 + 1) * DI + c] = silu_f(a1);
}

// ---------------- x_dbl projections via bf16x2 MFMA ----------------
// outputs: BsT/CsT (B,K,L,16) and raw dts (B,K,L,8-padded, cols 0..5 valid)
__global__ __launch_bounds__(256) void xdbl_mfma_kernel(const float* __restrict__ imgT,
    const float* __restrict__ xpw, float* __restrict__ dts_g,
    float* __restrict__ BsT, float* __restrict__ CsT) {
  __shared__ __align__(16) unsigned short Ah[64][104];
  __shared__ __align__(16) unsigned short Al[64][104];
  __shared__ __align__(16) unsigned short Wh[48][104];
  __shared__ __align__(16) unsigned short Wl[48][104];
  __shared__ int pos_s[64];

  int blk = blockIdx.x;            // (b*K+k)*64 + lt
  int lt = blk & 63;
  int bk = blk >> 6;
  int k = bk % K_, b = bk / K_;
  int l0 = lt * 64;
  int tid = threadIdx.x;
  int wid = tid >> 6;
  int lane = tid & 63;
  int mrow = lane & 15, quad = lane >> 4;

  if (tid < 64) pos_s[tid] = pos_kl(k, l0 + tid);
  __syncthreads();

  floatx4 acc[3];
#pragma unroll
  for (int q = 0; q < 3; q++) acc[q] = (floatx4)(0.f);

  const float* img_b = imgT + (size_t)b * L_ * DI;

  for (int kc = 0; kc < 2; kc++) {           // two K-chunks of 96
    if (kc) __syncthreads();
    for (int t = tid; t < 64 * 24; t += 256) {
      int li = t / 24, c4 = (t % 24) * 4;
      const float4 v = *(const float4*)&img_b[(size_t)pos_s[li] * DI + kc * 96 + c4];
      ushort4v h4, l4;
      float fv[4] = {v.x, v.y, v.z, v.w};
#pragma unroll
      for (int q = 0; q < 4; q++) {
        unsigned short hh = f2bf(fv[q]);
        h4[q] = hh;
        l4[q] = f2bf(fv[q] - bf2f(hh));
      }
      *(ushort4v*)&Ah[li][c4] = h4;
      *(ushort4v*)&Al[li][c4] = l4;
    }
    for (int t = tid; t < 48 * 24; t += 256) {
      int j = t / 24, c4 = (t % 24) * 4;
      ushort4v h4 = (ushort4v)0, l4 = (ushort4v)0;
      if (j < 38) {
        int c = (j < 32) ? (j + 6) : (j - 32);
        const float4 v = *(const float4*)&xpw[((size_t)(k * 38 + c)) * DI + kc * 96 + c4];
        float fv[4] = {v.x, v.y, v.z, v.w};
#pragma unroll
        for (int q = 0; q < 4; q++) {
          unsigned short hh = f2bf(fv[q]);
          h4[q] = hh;
          l4[q] = f2bf(fv[q] - bf2f(hh));
        }
      }
      *(ushort4v*)&Wh[j][c4] = h4;
      *(ushort4v*)&Wl[j][c4] = l4;
    }
    __syncthreads();
#pragma unroll
    for (int ks = 0; ks < 3; ks++) {
      short8 ah = *(const short8*)&Ah[wid * 16 + mrow][ks * 32 + quad * 8];
      short8 al = *(const short8*)&Al[wid * 16 + mrow][ks * 32 + quad * 8];
#pragma unroll
      for (int nt = 0; nt < 3; nt++) {
        short8 bh = *(const short8*)&Wh[nt * 16 + mrow][ks * 32 + quad * 8];
        short8 bl = *(const short8*)&Wl[nt * 16 + mrow][ks * 32 + quad * 8];
        acc[nt] = __builtin_amdgcn_mfma_f32_16x16x32_bf16(ah, bh, acc[nt], 0, 0, 0);
        acc[nt] = __builtin_amdgcn_mfma_f32_16x16x32_bf16(al, bh, acc[nt], 0, 0, 0);
        acc[nt] = __builtin_amdgcn_mfma_f32_16x16x32_bf16(ah, bl, acc[nt], 0, 0, 0);
      }
    }
  }
  size_t bkL = (size_t)(b * K_ + k) * L_ + l0;
#pragma unroll
  for (int rg = 0; rg < 4; rg++) {
    int grow = wid * 16 + quad * 4 + rg;
    size_t base = (bkL + grow) * NST;
    BsT[base + mrow] = acc[0][rg];
    CsT[base + mrow] = acc[1][rg];
    if (mrow < R_) dts_g[(bkL + grow) * 8 + mrow] = acc[2][rg];
  }
}

// ---------------- chunked scan pass 1 (register-resident; stores sum_dlt) ----
// grid: ((b*K+k)*NCH + c) ; 192 threads = one per channel d; 16 states/thread
// hend layout: [bk][c][n][d] ; sdl layout: [bk][c][d]
__global__ __launch_bounds__(192) void scan1_kernel(const float* __restrict__ imgT,
    const float* __restrict__ dts_g, const float* __restrict__ BsT,
    const float* __restrict__ a2g, const float* __restrict__ dtw,
    const float* __restrict__ dtb, float* __restrict__ hend,
    float* __restrict__ sdl) {
  __shared__ float bs_s[CL][NST];
  __shared__ float dt_s[CL][8];
  int blk = blockIdx.x;
  int c = blk % NCH;
  int tmp = blk / NCH;
  int k = tmp % K_, b = tmp / K_;
  int l0 = c * CL;
  int d = threadIdx.x;
  const float* img_b = imgT + (size_t)b * L_ * DI;
  {
    const float* Bs_bk = BsT + ((size_t)(b * K_ + k) * L_ + l0) * NST;
    for (int t = d; t < CL * NST; t += 192) bs_s[t >> 4][t & 15] = Bs_bk[t];
    const float* Dt = dts_g + ((size_t)(b * K_ + k) * L_ + l0) * 8;
    for (int t = d; t < CL * 8; t += 192) dt_s[t >> 3][t & 7] = Dt[t];
  }
  float A2[NST];
  {
    const floatx4* ap = (const floatx4*)(a2g + (size_t)(k * DI + d) * NST);
#pragma unroll
    for (int i = 0; i < 4; i++) {
      floatx4 v = ap[i];
      A2[4 * i] = v[0]; A2[4 * i + 1] = v[1]; A2[4 * i + 2] = v[2]; A2[4 * i + 3] = v[3];
    }
  }
  float w6[6], bias;
  {
    const float* wp = dtw + ((size_t)k * DI + d) * R_;
#pragma unroll
    for (int r = 0; r < 6; r++) w6[r] = wp[r];
    bias = dtb[k * DI + d];
  }
  // burst-load all u into registers (32 overlapped loads)
  float u[CL];
#pragma unroll
  for (int q = 0; q < CL; q++)
    u[q] = img_b[(size_t)pos_kl(k, l0 + q) * DI + d];
  __syncthreads();
  // pre-pass: all deltas out of the serial chain
  float dc[CL];
  float sum_dlt = 0.f;
#pragma unroll
  for (int q = 0; q < CL; q++) {
    const floatx4* dp = (const floatx4*)&dt_s[q][0];
    floatx4 d0 = dp[0], d1 = dp[1];
    float s = bias + w6[0] * d0[0] + w6[1] * d0[1] + w6[2] * d0[2]
                   + w6[3] * d0[3] + w6[4] * d1[0] + w6[5] * d1[1];
    dc[q] = softplus_fast(s);
    sum_dlt += dc[q];
  }
  float h[NST];
#pragma unroll
  for (int n = 0; n < NST; n++) h[n] = 0.f;
#pragma unroll
  for (int q = 0; q < CL; q++) {
    float du = dc[q] * u[q];
    floatx4 bsv[4];
    const floatx4* bp = (const floatx4*)&bs_s[q][0];
#pragma unroll
    for (int i = 0; i < 4; i++) bsv[i] = bp[i];
#pragma unroll
    for (int n = 0; n < NST; n++) {
      float dA = exp2_hw(dc[q] * A2[n]);
      h[n] = dA * h[n] + du * bsv[n >> 2][n & 3];
    }
  }
  size_t base = ((size_t)(b * K_ + k) * NCH + c) * (DI * NST) + d;
#pragma unroll
  for (int n = 0; n < NST; n++)
    hend[base + (size_t)n * DI] = h[n];
  sdl[((size_t)(b * K_ + k) * NCH + c) * DI + d] = sum_dlt;
}

// ---------------- carry sweep (aprod recomputed from sum_dlt) ----
// grid: (b*K+k)*DG + part ; thread owns flat (n,d) position
__global__ __launch_bounds__(256) void scan_carry_kernel(float* __restrict__ hend,
    const float* __restrict__ sdl, const float* __restrict__ a2g) {
  constexpr int PF = 8;
  int blk = blockIdx.x;
  int part = blk % DG;
  int bk = blk / DG;
  int k = bk % K_;
  const size_t DNS = (size_t)DI * NST;
  int idx = part * 256 + threadIdx.x;   // 0..3071
  int n = idx / DI;
  int d = idx - n * DI;
  float a2 = a2g[(size_t)(k * DI + d) * NST + n];
  size_t base  = (size_t)bk * NCH * DNS + idx;
  size_t sbase = (size_t)bk * NCH * DI + d;
  float hb[PF], ab[PF];
#pragma unroll
  for (int q = 0; q < PF; q++) {
    hb[q] = hend[base + (size_t)q * DNS];
    ab[q] = exp2_hw(a2 * sdl[sbase + (size_t)q * DI]);
  }
  float carry = 0.f;
  for (int c0 = 0; c0 < NCH; c0 += PF) {
    float hn[PF], an[PF];
    if (c0 + PF < NCH) {
#pragma unroll
      for (int q = 0; q < PF; q++) {
        hn[q] = hend[base + (size_t)(c0 + PF + q) * DNS];
        an[q] = exp2_hw(a2 * sdl[sbase + (size_t)(c0 + PF + q) * DI]);
      }
    } else {
#pragma unroll
      for (int q = 0; q < PF; q++) { hn[q] = 0.f; an[q] = 0.f; }
    }
#pragma unroll
    for (int q = 0; q < PF; q++) {
      hend[base + (size_t)(c0 + q) * DNS] = carry;   // carry entering chunk c0+q
      carry = ab[q] * carry + hb[q];
    }
#pragma unroll
    for (int q = 0; q < PF; q++) { hb[q] = hn[q]; ab[q] = an[q]; }
  }
}

// ---------------- scan pass 2, direction-paired (r5 form, y in LDS) ----
// grid: b*(2*NCH) + pr*NCH + c ; 192 threads = channel d
__global__ __launch_bounds__(192) void scan2_pair_kernel(const float* __restrict__ imgT,
    const float* __restrict__ dts_g, const float* __restrict__ BsT,
    const float* __restrict__ CsT, const float* __restrict__ a2g,
    const float* __restrict__ dtw, const float* __restrict__ dtb,
    const float* __restrict__ Ds, const float* __restrict__ carry_in,
    float* __restrict__ y02, float* __restrict__ y13) {
  __shared__ float bsf[CL][NST], csf[CL][NST], bsr[CL][NST], csr[CL][NST];
  __shared__ float dtf[CL][8], dtr[CL][8];
  __shared__ float y_lds[CL][DI];
  int blk = blockIdx.x;
  int c  = blk % NCH;
  int pr = (blk / NCH) & 1;
  int b  = blk / (2 * NCH);
  int kf = pr, kr = pr + 2;
  int p0 = c * CL;
  int d = threadIdx.x;
  const float* img_b = imgT + (size_t)b * L_ * DI;
  // stage B/C/dts for both directions (reverse rows flipped so index q aligns)
  {
    const float* Bf = BsT + ((size_t)(b * K_ + kf) * L_ + p0) * NST;
    const float* Cf = CsT + ((size_t)(b * K_ + kf) * L_ + p0) * NST;
    for (int t = d; t < CL * NST; t += 192) {
      bsf[t >> 4][t & 15] = Bf[t];
      csf[t >> 4][t & 15] = Cf[t];
    }
    const float* Br = BsT + (size_t)(b * K_ + kr) * L_ * NST;
    const float* Cr = CsT + (size_t)(b * K_ + kr) * L_ * NST;
    for (int t = d; t < CL * NST; t += 192) {
      int q = t >> 4, n = t & 15;
      size_t sr = (size_t)(L_ - 1 - p0 - q) * NST + n;
      bsr[q][n] = Br[sr];
      csr[q][n] = Cr[sr];
    }
    const float* Df = dts_g + ((size_t)(b * K_ + kf) * L_ + p0) * 8;
    for (int t = d; t < CL * 8; t += 192) dtf[t >> 3][t & 7] = Df[t];
    const float* Dr = dts_g + (size_t)(b * K_ + kr) * L_ * 8;
    for (int t = d; t < CL * 8; t += 192) {
      int q = t >> 3, r = t & 7;
      dtr[q][r] = Dr[(size_t)(L_ - 1 - p0 - q) * 8 + r];
    }
  }
  // burst-load u (shared by both directions)
  float u[CL];
#pragma unroll
  for (int q = 0; q < CL; q++)
    u[q] = img_b[(size_t)pos_pair(pr, p0 + q) * DI + d];
  float dsum = 0.f;
  if (pr == 0) dsum = Ds[d] + Ds[DI + d] + Ds[2 * DI + d] + Ds[3 * DI + d];
  __syncthreads();
  float A2[NST], h[NST], w6[6], bias, dc[CL];
  // ---- loop 1: forward direction kf, positions ascending ----
  {
    const floatx4* ap = (const floatx4*)(a2g + (size_t)(kf * DI + d) * NST);
#pragma unroll
    for (int i = 0; i < 4; i++) {
      floatx4 v = ap[i];
      A2[4 * i] = v[0]; A2[4 * i + 1] = v[1]; A2[4 * i + 2] = v[2]; A2[4 * i + 3] = v[3];
    }
    size_t cb = ((size_t)(b * K_ + kf) * NCH + c) * (DI * NST) + d;
#pragma unroll
    for (int n = 0; n < NST; n++) h[n] = carry_in[cb + (size_t)n * DI];
    const float* wp = dtw + ((size_t)kf * DI + d) * R_;
#pragma unroll
    for (int r = 0; r < 6; r++) w6[r] = wp[r];
    bias = dtb[kf * DI + d];
  }
#pragma unroll
  for (int q = 0; q < CL; q++) {
    const floatx4* dp = (const floatx4*)&dtf[q][0];
    floatx4 d0 = dp[0], d1 = dp[1];
    float s = bias + w6[0] * d0[0] + w6[1] * d0[1] + w6[2] * d0[2]
                   + w6[3] * d0[3] + w6[4] * d1[0] + w6[5] * d1[1];
    dc[q] = softplus_fast(s);
  }
#pragma unroll
  for (int q = 0; q < CL; q++) {
    float du = dc[q] * u[q];
    floatx4 bsv[4], csv[4];
    const floatx4* bp = (const floatx4*)&bsf[q][0];
    const floatx4* cp = (const floatx4*)&csf[q][0];
#pragma unroll
    for (int i = 0; i < 4; i++) { bsv[i] = bp[i]; csv[i] = cp[i]; }
    float yq = dsum * u[q];
#pragma unroll
    for (int n = 0; n < NST; n++) {
      float dA = exp2_hw(dc[q] * A2[n]);
      h[n] = dA * h[n] + du * bsv[n >> 2][n & 3];
      yq += h[n] * csv[n >> 2][n & 3];
    }
    y_lds[q][d] = yq;   // own-thread slot; no barrier needed
  }
  // ---- loop 2: reverse direction kr, positions descending (steps ascend) ----
  {
    const floatx4* ap = (const floatx4*)(a2g + (size_t)(kr * DI + d) * NST);
#pragma unroll
    for (int i = 0; i < 4; i++) {
      floatx4 v = ap[i];
      A2[4 * i] = v[0]; A2[4 * i + 1] = v[1]; A2[4 * i + 2] = v[2]; A2[4 * i + 3] = v[3];
    }
    size_t cb = ((size_t)(b * K_ + kr) * NCH + (NCH - 1 - c)) * (DI * NST) + d;
#pragma unroll
    for (int n = 0; n < NST; n++) h[n] = carry_in[cb + (size_t)n * DI];
    const float* wp = dtw + ((size_t)kr * DI + d) * R_;
#pragma unroll
    for (int r = 0; r < 6; r++) w6[r] = wp[r];
    bias = dtb[kr * DI + d];
  }
#pragma unroll
  for (int q = 0; q < CL; q++) {
    const floatx4* dp = (const floatx4*)&dtr[q][0];
    floatx4 d0 = dp[0], d1 = dp[1];
    float s = bias + w6[0] * d0[0] + w6[1] * d0[1] + w6[2] * d0[2]
                   + w6[3] * d0[3] + w6[4] * d1[0] + w6[5] * d1[1];
    dc[q] = softplus_fast(s);
  }
  float* yout = (pr == 0) ? y02 : y13;
#pragma unroll
  for (int qq = 0; qq < CL; qq++) {
    int q = CL - 1 - qq;
    float du = dc[q] * u[q];
    floatx4 bsv[4], csv[4];
    const floatx4* bp = (const floatx4*)&bsr[q][0];
    const floatx4* cp = (const floatx4*)&csr[q][0];
#pragma unroll
    for (int i = 0; i < 4; i++) { bsv[i] = bp[i]; csv[i] = cp[i]; }
    float yq = y_lds[q][d];
#pragma unroll
    for (int n = 0; n < NST; n++) {
      float dA = exp2_hw(dc[q] * A2[n]);
      h[n] = dA * h[n] + du * bsv[n >> 2][n & 3];
      yq += h[n] * csv[n >> 2][n & 3];
    }
    yout[((size_t)b * L_ + pos_pair(pr, p0 + q)) * DI + d] = yq;
  }
}

// ---------------- fused: LN(y02+y13)*silu(z) -> out_proj MFMA + residual ----
// grid: M/64 blocks, 256 threads. LDS zg rows padded to 193 (conflict-free).
__global__ __launch_bounds__(256) void lnz_outproj_kernel(const float* __restrict__ y02,
    const float* __restrict__ y13, const float* __restrict__ lg,
    const float* __restrict__ lb, const float* __restrict__ z,
    const unsigned short* __restrict__ wo, const float* __restrict__ x,
    float* __restrict__ x_res) {
  __shared__ __align__(16) unsigned short Wh[96][104];
  __shared__ __align__(16) unsigned short Wl[96][104];
  __shared__ float zg[64][193];
  __shared__ float stat_mean[64], stat_inv[64];
  int row0 = blockIdx.x * 64;
  int tid = threadIdx.x;
  int wv = tid >> 6, lane = tid & 63, mrow = lane & 15, quad = lane >> 4;
  // phase A: stage v = y02 + y13
  for (int t = tid; t < 64 * DI; t += 256) {
    int r = t / DI, c = t - r * DI;
    size_t gi = (size_t)(row0 + r) * DI + c;
    zg[r][c] = y02[gi] + y13[gi];
  }
  __syncthreads();
  // phase B: row stats, 4 threads per row + 2 shuffle combines
  {
    int r = tid >> 2, part = tid & 3;
    float s = 0.f, s2 = 0.f;
#pragma unroll 4
    for (int i = 0; i < 48; i++) {
      float v = zg[r][part * 48 + i];
      s += v; s2 += v * v;
    }
    s  += __shfl_xor(s, 1, 64);  s  += __shfl_xor(s, 2, 64);
    s2 += __shfl_xor(s2, 1, 64); s2 += __shfl_xor(s2, 2, 64);
    if (part == 0) {
      float mean = s * (1.f / DI);
      float var  = s2 * (1.f / DI) - mean * mean;
      stat_mean[r] = mean;
      stat_inv[r]  = rsqrtf(var + 1e-5f);
    }
  }
  __syncthreads();
  // phase C: apply LN + silu(z) gate in place
  for (int t = tid; t < 64 * DI; t += 256) {
    int r = t / DI, c = t - r * DI;
    size_t gi = (size_t)(row0 + r) * DI + c;
    float zv = z[gi];
    zg[r][c] = ((zg[r][c] - stat_mean[r]) * stat_inv[r] * lg[c] + lb[c]) * silu_f(zv);
  }
  __syncthreads();
  // phase D: MFMA  x_res = zg @ wo^T + x
  floatx4 acc[6];
#pragma unroll
  for (int q = 0; q < 6; q++) acc[q] = (floatx4)(0.f);
  for (int kc = 0; kc < 2; kc++) {     // 2 K-chunks of 96
    if (kc) __syncthreads();
    for (int t = tid; t < 96 * 12; t += 256) {
      int j = t / 12, u = t % 12;
      *(short8*)&Wh[j][u * 8] = *(const short8*)&wo[(size_t)j * DI + kc * 96 + u * 8];
      *(short8*)&Wl[j][u * 8] = *(const short8*)&wo[18432 + (size_t)j * DI + kc * 96 + u * 8];
    }
    __syncthreads();
#pragma unroll
    for (int ks = 0; ks < 3; ks++) {
      const float* zr = &zg[wv * 16 + mrow][kc * 96 + ks * 32 + quad * 8];
      short8 ah, al;
#pragma unroll
      for (int q = 0; q < 8; q++) {
        float f = zr[q];
        unsigned short hv = f2bf(f);
        ah[q] = (short)hv;
        al[q] = (short)f2bf(f - bf2f(hv));
      }
#pragma unroll
      for (int nt = 0; nt < 6; nt++) {
        short8 bh = *(const short8*)&Wh[nt * 16 + mrow][ks * 32 + quad * 8];
        short8 bl = *(const short8*)&Wl[nt * 16 + mrow][ks * 32 + quad * 8];
        acc[nt] = __builtin_amdgcn_mfma_f32_16x16x32_bf16(ah, bh, acc[nt], 0, 0, 0);
        acc[nt] = __builtin_amdgcn_mfma_f32_16x16x32_bf16(al, bh, acc[nt], 0, 0, 0);
        acc[nt] = __builtin_amdgcn_mfma_f32_16x16x32_bf16(ah, bl, acc[nt], 0, 0, 0);
      }
    }
  }
#pragma unroll
  for (int nt = 0; nt < 6; nt++) {
    int j = nt * 16 + mrow;
#pragma unroll
    for (int rg = 0; rg < 4; rg++) {
      int row = row0 + wv * 16 + quad * 4 + rg;
      x_res[(size_t)row * C_ + j] = x[(size_t)row * C_ + j] + acc[nt][rg];
    }
  }
}

// ---------------- weight prep: pack [bw|sw] per layer into bf16 Wcat[3][96][864] ----------------
__global__ __launch_bounds__(256) void prepw_kernel(const float* __restrict__ bw1,
    const float* __restrict__ sw1, const float* __restrict__ bw2,
    const float* __restrict__ sw2, const float* __restrict__ bw3,
    const float* __restrict__ sw3, unsigned short* __restrict__ wcat) {
  int idx = blockIdx.x * 256 + threadIdx.x;
  if (idx >= 3 * KLAY) return;
  int layer = idx / KLAY, rem = idx % KLAY;
  int j = rem / KANK, k = rem % KANK;
  const float* bw = (layer == 0) ? bw1 : (layer == 1) ? bw2 : bw3;
  const float* sw = (layer == 0) ? sw1 : (layer == 1) ? sw2 : sw3;
  float v = (k < C_) ? bw[j * C_ + k] : sw[j * 768 + (k - C_)];
  wcat[idx] = f2bf(v);
}

// ---------------- KAN linear via bf16 MFMA ----------------
// 32-row tile, 256 threads (4 waves): wave (rh,ch) owns rows rh*16.. and cols ch*48..
__global__ __launch_bounds__(256) void kan_mfma_kernel(const float* __restrict__ in,
    const unsigned short* __restrict__ wl, float* __restrict__ out) {
  __shared__ __align__(16) float x_s[32][100];
  __shared__ __align__(16) unsigned short A_s[32][104];
  __shared__ __align__(16) unsigned short W_s[96][104];
  int row0 = blockIdx.x * 32;
  int tid = threadIdx.x;
  for (int t = tid; t < 32 * 24; t += 256) {
    int r = t / 24, c4 = (t % 24) * 4;
    *(float4*)&x_s[r][c4] = *(const float4*)&in[(size_t)(row0 + r) * C_ + c4];
  }
  floatx4 acc[3];
#pragma unroll
  for (int q = 0; q < 3; q++) acc[q] = (floatx4)(0.f);
  int wv = tid >> 6;
  int rh = wv >> 1, ch = wv & 1;
  int lane = tid & 63;
  int mrow = lane & 15, quad = lane >> 4;
  __syncthreads();
  for (int ci = 0; ci < 9; ci++) {
    if (ci) __syncthreads();
    for (int t = tid; t < 96 * 12; t += 256) {
      int j = t / 12, u = t % 12;
      *(short8*)&W_s[j][u * 8] =
          *(const short8*)&wl[(size_t)j * KANK + ci * 96 + u * 8];
    }
    if (ci == 0) {
      for (int t = tid; t < 32 * 48; t += 256) {
        int r = t / 48, k2 = (t % 48) * 2;
        unsigned v = (unsigned)f2bf(silu_f(x_s[r][k2])) |
                     ((unsigned)f2bf(silu_f(x_s[r][k2 + 1])) << 16);
        *(unsigned*)&A_s[r][k2] = v;
      }
    } else {
      int c0 = (ci - 1) * 12;
      for (int t = tid; t < 32 * 12; t += 256) {
        int r = t & 31, cl = t >> 5;   // cl 0..11
        float x = x_s[r][c0 + cl];
        float bb[11];
        spline8(x, bb);
        short8 av;
#pragma unroll
        for (int q = 0; q < 8; q++) av[q] = (short)f2bf(bb[q]);
        *(short8*)&A_s[r][cl * 8] = av;
      }
    }
    __syncthreads();
#pragma unroll
    for (int ks = 0; ks < 3; ks++) {
      short8 a = *(const short8*)&A_s[rh * 16 + mrow][ks * 32 + quad * 8];
#pragma unroll
      for (int ct = 0; ct < 3; ct++) {
        short8 b = *(const short8*)&W_s[ch * 48 + ct * 16 + mrow][ks * 32 + quad * 8];
        acc[ct] = __builtin_amdgcn_mfma_f32_16x16x32_bf16(a, b, acc[ct], 0, 0, 0);
      }
    }
  }
#pragma unroll
  for (int ct = 0; ct < 3; ct++)
#pragma unroll
    for (int rg = 0; rg < 4; rg++) {
      int row = row0 + rh * 16 + quad * 4 + rg;
      out[(size_t)row * C_ + ch * 48 + ct * 16 + mrow] = acc[ct][rg];
    }
}

// ---------------- depthwise 3x3 + BN-ish scale + ReLU (+ optional residual) ----------------
// 4 pixels per block: threads 0..95 -> pixels (p0,p0+1), 96..191 -> (p0+2,p0+3)
__global__ __launch_bounds__(192) void dwbn_kernel(const float* __restrict__ t,
    const float* __restrict__ w, const float* __restrict__ bias,
    const float* __restrict__ gamma, const float* __restrict__ beta,
    const float* __restrict__ addres, float* __restrict__ out) {
  int tid = threadIdx.x;
  int half = (tid >= 96) ? 1 : 0;
  int c = tid - half * 96;
  int p0 = blockIdx.x * 4 + half * 2;
  int b = p0 >> 12;
  int ij = p0 & 4095;
  int i = ij >> 6, j0 = ij & 63;   // j0 even, j0+1 <= 63
  float v[3][4];
#pragma unroll
  for (int r = 0; r < 3; r++) {
    int ii = i - 1 + r;
    bool rok = (ii >= 0 && ii < H_);
#pragma unroll
    for (int cc = 0; cc < 4; cc++) {
      int jj = j0 - 1 + cc;
      v[r][cc] = (rok && jj >= 0 && jj < W_)
                     ? t[((size_t)b * L_ + ii * W_ + jj) * C_ + c] : 0.f;
    }
  }
  const float* wc = w + c * 9;
  float wv[9];
#pragma unroll
  for (int q = 0; q < 9; q++) wv[q] = wc[q];
  float a0 = bias[c], a1 = a0;
#pragma unroll
  for (int r = 0; r < 3; r++) {
#pragma unroll
    for (int tt = 0; tt < 3; tt++) {
      a0 += v[r][tt]     * wv[r * 3 + tt];
      a1 += v[r][tt + 1] * wv[r * 3 + tt];
    }
  }
  float gsc = gamma[c] * rsqrtf(1.f + 1e-5f);
  float bt = beta[c];
  float o0 = fmaxf(a0 * gsc + bt, 0.f);
  float o1 = fmaxf(a1 * gsc + bt, 0.f);
  if (addres != nullptr) {
    o0 += addres[(size_t)p0 * C_ + c];
    o1 += addres[(size_t)(p0 + 1) * C_ + c];
  }
  out[(size_t)p0 * C_ + c]       = o0;
  out[(size_t)(p0 + 1) * C_ + c] = o1;
}

// ---------------- host launcher ----------------
extern "C" void kernel_launch(void* const* d_in, const int* in_sizes, int n_in,
                              void* d_out, int out_size, void* d_ws, size_t ws_size,
                              hipStream_t stream) {
  const float* x         = (const float*)d_in[0];
  const float* norm1_g   = (const float*)d_in[3];
  const float* norm1_b   = (const float*)d_in[4];
  const float* in_proj_w = (const float*)d_in[5];
  const float* conv_w    = (const float*)d_in[6];
  const float* conv_b    = (const float*)d_in[7];
  const float* x_proj_w  = (const float*)d_in[8];
  const float* dt_w      = (const float*)d_in[9];
  const float* dt_b      = (const float*)d_in[10];
  const float* A_logs    = (const float*)d_in[11];
  const float* Ds        = (const float*)d_in[12];
  const float* out_ng    = (const float*)d_in[13];
  const float* out_nb    = (const float*)d_in[14];
  const float* out_proj_w= (const float*)d_in[15];
  const float* norm2_g   = (const float*)d_in[16];
  const float* norm2_b   = (const float*)d_in[17];
  const float* fc1_bw    = (const float*)d_in[18];
  const float* fc1_sw    = (const float*)d_in[19];
  const float* fc2_bw    = (const float*)d_in[20];
  const float* fc2_sw    = (const float*)d_in[21];
  const float* fc3_bw    = (const float*)d_in[22];
  const float* fc3_sw    = (const float*)d_in[23];
  const float* dw1_w     = (const float*)d_in[24];
  const float* dw1_b     = (const float*)d_in[25];
  const float* dw1_g     = (const float*)d_in[26];
  const float* dw1_be    = (const float*)d_in[27];
  const float* dw2_w     = (const float*)d_in[28];
  const float* dw2_b     = (const float*)d_in[29];
  const float* dw2_g     = (const float*)d_in[30];
  const float* dw2_be    = (const float*)d_in[31];
  const float* dw3_w     = (const float*)d_in[32];
  const float* dw3_b     = (const float*)d_in[33];
  const float* dw3_g     = (const float*)d_in[34];
  const float* dw3_be    = (const float*)d_in[35];

  float* ws = (float*)d_ws;
  float* h_buf   = ws;                       // M*96
  float* xin_buf = h_buf + (size_t)M_ * C_;  // M*192 (reused as y13 after conv)
  float* z_buf   = xin_buf + (size_t)M_ * DI;
  float* imgT    = z_buf + (size_t)M_ * DI;
  float* BsT     = imgT + (size_t)M_ * DI;                 // B*K*L*16
  float* CsT     = BsT + (size_t)B_ * K_ * L_ * NST;
  float* y_pre   = CsT + (size_t)B_ * K_ * L_ * NST;       // M*192 (= y02)
  float* x_res   = y_pre + (size_t)M_ * DI;                // M*96
  float* t_a     = x_res + (size_t)M_ * C_;                // M*96
  float* t_b     = t_a + (size_t)M_ * C_;                  // M*96
  float* hend    = t_b + (size_t)M_ * C_;                  // B*K*NCH*DI*NST
  float* sdl_buf = hend + (size_t)B_ * K_ * NCH * DI * NST; // B*K*NCH*DI (1.5MB)
  float* a2_buf  = sdl_buf + (size_t)B_ * K_ * NCH * DI;    // K*DI*NST = 12288
  // aliases (lifetimes disjoint):
  float* dts_g   = t_a;                        // B*K*L*8 floats; t_a used only post-scan
  unsigned short* wio  = (unsigned short*)t_b; // in_proj hi/lo bf16; t_b used only post-scan
  unsigned short* wo_p = wio + 2 * 36864;      // out_proj hi/lo bf16 (t_b slack, 74KB)
  float* y13     = xin_buf;                    // xin dead after conv
  unsigned short* wcat = (unsigned short*)BsT; // bf16 KAN weights; BsT dead after scan2

  // 1. LN1
  ln96_kernel<<<M_ / 4, 256, 0, stream>>>(x, norm1_g, norm1_b, h_buf);
  // 2. in_proj -> xin, z  (bf16 hi/lo MFMA)
  prep_inproj_kernel<<<144, 256, 0, stream>>>(in_proj_w, wio);
  prep_outproj_kernel<<<72, 256, 0, stream>>>(out_proj_w, wo_p);
  prep_a2_kernel<<<48, 256, 0, stream>>>(A_logs, a2_buf);
  gemm_in_mfma_kernel<<<(M_ / 64) * 2, 256, 0, stream>>>(h_buf, wio, xin_buf, z_buf);
  // 3. dwconv + silu -> imgT (NHWC), 2 px/block
  conv_silu_kernel<<<M_ / 2, 192, 0, stream>>>(xin_buf, conv_w, conv_b, imgT);
  // 4. x_dbl projections (bf16x2 MFMA) -> BsT, CsT, dts
  xdbl_mfma_kernel<<<B_ * K_ * (L_ / 64), 256, 0, stream>>>(imgT, x_proj_w, dts_g,
                                                            BsT, CsT);
  // 5. chunked selective scan
  scan1_kernel<<<B_ * K_ * NCH, 192, 0, stream>>>(imgT, dts_g, BsT, a2_buf,
                                                  dt_w, dt_b, hend, sdl_buf);
  scan_carry_kernel<<<B_ * K_ * DG, 256, 0, stream>>>(hend, sdl_buf, a2_buf);
  scan2_pair_kernel<<<B_ * 2 * NCH, 192, 0, stream>>>(imgT, dts_g, BsT, CsT, a2_buf,
                                                      dt_w, dt_b, Ds, hend,
                                                      y_pre, y13);
  // 5b. pack KAN weights to bf16 (BsT region is dead from here on)
  prepw_kernel<<<(3 * KLAY + 255) / 256, 256, 0, stream>>>(fc1_bw, fc1_sw, fc2_bw,
                                                           fc2_sw, fc3_bw, fc3_sw, wcat);
  // 6+7. fused: out-norm LN + silu(z) gate + out_proj MFMA + residual
  lnz_outproj_kernel<<<M_ / 64, 256, 0, stream>>>(y_pre, y13, out_ng, out_nb,
                                                  z_buf, wo_p, x, x_res);
  // 8. LN2
  ln96_kernel<<<M_ / 4, 256, 0, stream>>>(x_res, norm2_g, norm2_b, h_buf);
  // 9. KAN (bf16 MFMA) / dw-bn-relu chain (dwbn: 4 px/block)
  kan_mfma_kernel<<<M_ / 32, 256, 0, stream>>>(h_buf, wcat, t_a);
  dwbn_kernel<<<M_ / 4, 192, 0, stream>>>(t_a, dw1_w, dw1_b, dw1_g, dw1_be, nullptr, t_b);
  kan_mfma_kernel<<<M_ / 32, 256, 0, stream>>>(t_b, wcat + KLAY, t_a);
  dwbn_kernel<<<M_ / 4, 192, 0, stream>>>(t_a, dw2_w, dw2_b, dw2_g, dw2_be, nullptr, t_b);
  kan_mfma_kernel<<<M_ / 32, 256, 0, stream>>>(t_b, wcat + 2 * KLAY, t_a);
  dwbn_kernel<<<M_ / 4, 192, 0, stream>>>(t_a, dw3_w, dw3_b, dw3_g, dw3_be, x_res, (float*)d_out);
}

// Round 13
// 419.882 us; speedup vs baseline: 1.0226x; 1.0226x over previous
//
#include <hip/hip_runtime.h>
#include <math.h>

// Problem constants (fixed shapes from setup_inputs)
constexpr int B_  = 4;
constexpr int H_  = 64;
constexpr int W_  = 64;
constexpr int C_  = 96;
constexpr int L_  = H_ * W_;        // 4096
constexpr int DI  = 192;            // 2*C
constexpr int K_  = 4;
constexpr int NST = 16;
constexpr int R_  = 6;
constexpr int M_  = B_ * L_;        // 16384 rows

// chunked-scan params
constexpr int NCH = 128;            // number of chunks along L
constexpr int CL  = 32;             // chunk length (NCH*CL == L_)
constexpr int DG  = 12;             // flat partitions of DI*NST/256 in carry kernel

// KAN GEMM params
constexpr int KANK = 864;           // 96 silu + 96*8 spline features
constexpr int KLAY = 96 * KANK;     // 82944 weights per layer

typedef __attribute__((ext_vector_type(8))) short short8;
typedef __attribute__((ext_vector_type(4))) float floatx4;
typedef __attribute__((ext_vector_type(4))) unsigned short ushort4v;

// ---------------- helpers ----------------
__device__ __forceinline__ float wave_sum64(float v) {
#pragma unroll
  for (int off = 1; off < 64; off <<= 1) v += __shfl_xor(v, off, 64);
  return v;
}

__device__ __forceinline__ float exp2_hw(float x) {
  return __builtin_amdgcn_exp2f(x);   // v_exp_f32 (2^x), no mul
}

// spatial position read/written by direction k at scan step l
__device__ __forceinline__ int pos_kl(int k, int l) {
  int ll = (k >= 2) ? (L_ - 1 - l) : l;
  int i = ll & 63;      // row
  int j = ll >> 6;      // diag index
  int col = ((k & 1) == 0) ? ((i + j) & 63) : ((j - i) & 63);
  return (i << 6) + col;
}

// position for pair pr at position-index ll (same for both k of the pair)
__device__ __forceinline__ int pos_pair(int pr, int ll) {
  int i = ll & 63, j = ll >> 6;
  int col = (pr == 0) ? ((i + j) & 63) : ((j - i) & 63);
  return (i << 6) + col;
}

__device__ __forceinline__ float silu_f(float x) {
  return x / (1.f + __expf(-x));
}

// fast softplus: __logf is hw v_log_f32, arg in (1,2] -> ~1ulp
__device__ __forceinline__ float softplus_fast(float s) {
  return fmaxf(s, 0.f) + __logf(1.f + __expf(-fabsf(s)));
}

__device__ __forceinline__ unsigned short f2bf(float f) {
  unsigned u = __float_as_uint(f);
  unsigned r = (u + 0x7FFFu + ((u >> 16) & 1u)) >> 16;
  return (unsigned short)r;
}

__device__ __forceinline__ float bf2f(unsigned short h) {
  return __uint_as_float(((unsigned)h) << 16);
}

// compute the 8 cubic B-spline bases for scalar x (grid g_i = 0.4i - 2.2)
__device__ __forceinline__ void spline8(float x, float* bb /*len 11*/) {
#pragma unroll
  for (int i2 = 0; i2 < 11; i2++) {
    float g0 = 0.4f * i2 - 2.2f;
    float g1 = 0.4f * i2 - 1.8f;
    bb[i2] = (x >= g0 && x < g1) ? 1.f : 0.f;
  }
#pragma unroll
  for (int k2 = 1; k2 <= 3; k2++) {
    float invd = 1.f / (0.4f * k2);
#pragma unroll
    for (int i2 = 0; i2 + k2 < 11; i2++) {
      float gi   = 0.4f * i2 - 2.2f;
      float gik1 = 0.4f * (i2 + k2 + 1) - 2.2f;
      bb[i2] = (x - gi) * invd * bb[i2] + (gik1 - x) * invd * bb[i2 + 1];
    }
  }
}

// ---------------- LN over C=96, one wave per row ----------------
__global__ __launch_bounds__(256) void ln96_kernel(const float* __restrict__ in,
    const float* __restrict__ g, const float* __restrict__ b,
    float* __restrict__ out) {
  int wave = blockIdx.x * 4 + (threadIdx.x >> 6);
  int lane = threadIdx.x & 63;
  const float* rp = in + (size_t)wave * C_;
  float v0 = rp[lane];
  float v1 = (lane < C_ - 64) ? rp[lane + 64] : 0.f;
  float s  = wave_sum64(v0 + v1);
  float s2 = wave_sum64(v0 * v0 + v1 * v1);
  float mean = s * (1.f / C_);
  float var  = s2 * (1.f / C_) - mean * mean;
  float inv  = rsqrtf(var + 1e-5f);
  float* op = out + (size_t)wave * C_;
  op[lane] = (v0 - mean) * inv * g[lane] + b[lane];
  if (lane < C_ - 64) op[lane + 64] = (v1 - mean) * inv * g[lane + 64] + b[lane + 64];
}

// ---------------- pack in_proj_w into hi/lo bf16 (once per launch) ----------------
__global__ __launch_bounds__(256) void prep_inproj_kernel(const float* __restrict__ w,
    unsigned short* __restrict__ wio) {
  int idx = blockIdx.x * 256 + threadIdx.x;  // 384*96 = 36864
  if (idx >= 384 * 96) return;
  float v = w[idx];
  unsigned short hh = f2bf(v);
  wio[idx] = hh;
  wio[36864 + idx] = f2bf(v - bf2f(hh));
}

// ---------------- pack out_proj_w (96x192) into hi/lo bf16 ----------------
__global__ __launch_bounds__(256) void prep_outproj_kernel(const float* __restrict__ w,
    unsigned short* __restrict__ wo) {
  int idx = blockIdx.x * 256 + threadIdx.x;  // 96*192 = 18432
  if (idx >= 96 * 192) return;
  float v = w[idx];
  unsigned short hh = f2bf(v);
  wo[idx] = hh;
  wo[18432 + idx] = f2bf(v - bf2f(hh));
}

// ---------------- A2 table: -exp(A_logs)*log2(e), [K*DI][NST] ----------------
__global__ __launch_bounds__(256) void prep_a2_kernel(const float* __restrict__ A_logs,
    float* __restrict__ a2g) {
  int idx = blockIdx.x * 256 + threadIdx.x;  // K*DI*NST = 12288
  if (idx < K_ * DI * NST) a2g[idx] = -__expf(A_logs[idx]) * 1.44269504f;
}

// ---------------- in_proj via bf16 hi/lo MFMA ----------------
// grid: (M/64)*2 blocks; block handles 64 rows x 2 N-chunks of 96
__global__ __launch_bounds__(256) void gemm_in_mfma_kernel(const float* __restrict__ h,
    const unsigned short* __restrict__ wio, float* __restrict__ xin,
    float* __restrict__ z) {
  __shared__ __align__(16) unsigned short Wh[96][104];
  __shared__ __align__(16) unsigned short Wl[96][104];
  int row0 = (blockIdx.x >> 1) * 64;
  int nc0  = (blockIdx.x & 1) * 2;
  int tid = threadIdx.x;
  int wv = tid >> 6, lane = tid & 63, mrow = lane & 15, quad = lane >> 4;

  short8 ah[3], al[3];
  const float* hr = h + (size_t)(row0 + wv * 16 + mrow) * C_;
#pragma unroll
  for (int ks = 0; ks < 3; ks++) {
    float4 va = *(const float4*)&hr[ks * 32 + quad * 8];
    float4 vb = *(const float4*)&hr[ks * 32 + quad * 8 + 4];
    float f[8] = {va.x, va.y, va.z, va.w, vb.x, vb.y, vb.z, vb.w};
    short8 hh, ll;
#pragma unroll
    for (int q = 0; q < 8; q++) {
      unsigned short hv = f2bf(f[q]);
      hh[q] = (short)hv;
      ll[q] = (short)f2bf(f[q] - bf2f(hv));
    }
    ah[ks] = hh; al[ks] = ll;
  }
  for (int nci = 0; nci < 2; nci++) {       // 2 chunks of 96 output cols
    int nc = nc0 + nci;
    if (nci) __syncthreads();
    for (int t = tid; t < 96 * 12; t += 256) {
      int j = t / 12, u = t % 12;
      *(short8*)&Wh[j][u * 8] = *(const short8*)&wio[(size_t)(nc * 96 + j) * 96 + u * 8];
      *(short8*)&Wl[j][u * 8] = *(const short8*)&wio[(size_t)(384 + nc * 96 + j) * 96 + u * 8];
    }
    __syncthreads();
    floatx4 acc[6];
#pragma unroll
    for (int q = 0; q < 6; q++) acc[q] = (floatx4)(0.f);
#pragma unroll
    for (int ks = 0; ks < 3; ks++) {
#pragma unroll
      for (int nt = 0; nt < 6; nt++) {
        short8 bh = *(const short8*)&Wh[nt * 16 + mrow][ks * 32 + quad * 8];
        short8 bl = *(const short8*)&Wl[nt * 16 + mrow][ks * 32 + quad * 8];
        acc[nt] = __builtin_amdgcn_mfma_f32_16x16x32_bf16(ah[ks], bh, acc[nt], 0, 0, 0);
        acc[nt] = __builtin_amdgcn_mfma_f32_16x16x32_bf16(al[ks], bh, acc[nt], 0, 0, 0);
        acc[nt] = __builtin_amdgcn_mfma_f32_16x16x32_bf16(ah[ks], bl, acc[nt], 0, 0, 0);
      }
    }
#pragma unroll
    for (int nt = 0; nt < 6; nt++) {
      int j = nc * 96 + nt * 16 + mrow;
#pragma unroll
      for (int rg = 0; rg < 4; rg++) {
        int row = row0 + wv * 16 + quad * 4 + rg;
        float v = acc[nt][rg];
        if (j < DI) xin[(size_t)row * DI + j] = v;
        else        z[(size_t)row * DI + (j - DI)] = v;
      }
    }
  }
}

// ---------------- depthwise 3x3 conv (NHWC) + SiLU, 2 pixels/block ----------------
__global__ __launch_bounds__(192) void conv_silu_kernel(const float* __restrict__ xin,
    const float* __restrict__ cw, const float* __restrict__ cb, float* __restrict__ imgT) {
  int p0 = blockIdx.x * 2;
  int b = p0 >> 12;
  int ij = p0 & 4095;
  int i = ij >> 6, j0 = ij & 63;   // j0 even, j0+1 <= 63
  int c = threadIdx.x;
  float v[3][4];
#pragma unroll
  for (int r = 0; r < 3; r++) {
    int ii = i - 1 + r;
    bool rok = (ii >= 0 && ii < H_);
#pragma unroll
    for (int cc = 0; cc < 4; cc++) {
      int jj = j0 - 1 + cc;
      v[r][cc] = (rok && jj >= 0 && jj < W_)
                     ? xin[((size_t)b * L_ + ii * W_ + jj) * DI + c] : 0.f;
    }
  }
  const float* wc = cw + c * 9;
  float w[9];
#pragma unroll
  for (int q = 0; q < 9; q++) w[q] = wc[q];
  float a0 = cb[c], a1 = a0;
#pragma unroll
  for (int r = 0; r < 3; r++) {
#pragma unroll
    for (int t = 0; t < 3; t++) {
      a0 += v[r][t]     * w[r * 3 + t];
      a1 += v[r][t + 1] * w[r * 3 + t];
    }
  }
  imgT[(size_t)p0 * DI + c]       = silu_f(a0);
  imgT[(size_t)(p0 + 1) * DI + c] = silu_f(a1);
}

// ---------------- x_dbl projections via bf16x2 MFMA ----------------
// outputs: BsT/CsT (B,K,L,16) and raw dts (B,K,L,8-padded, cols 0..5 valid)
__global__ __launch_bounds__(256) void xdbl_mfma_kernel(const float* __restrict__ imgT,
    const float* __restrict__ xpw, float* __restrict__ dts_g,
    float* __restrict__ BsT, float* __restrict__ CsT) {
  __shared__ __align__(16) unsigned short Ah[64][104];
  __shared__ __align__(16) unsigned short Al[64][104];
  __shared__ __align__(16) unsigned short Wh[48][104];
  __shared__ __align__(16) unsigned short Wl[48][104];
  __shared__ int pos_s[64];

  int blk = blockIdx.x;            // (b*K+k)*64 + lt
  int lt = blk & 63;
  int bk = blk >> 6;
  int k = bk % K_, b = bk / K_;
  int l0 = lt * 64;
  int tid = threadIdx.x;
  int wid = tid >> 6;
  int lane = tid & 63;
  int mrow = lane & 15, quad = lane >> 4;

  if (tid < 64) pos_s[tid] = pos_kl(k, l0 + tid);
  __syncthreads();

  floatx4 acc[3];
#pragma unroll
  for (int q = 0; q < 3; q++) acc[q] = (floatx4)(0.f);

  const float* img_b = imgT + (size_t)b * L_ * DI;

  for (int kc = 0; kc < 2; kc++) {           // two K-chunks of 96
    if (kc) __syncthreads();
    for (int t = tid; t < 64 * 24; t += 256) {
      int li = t / 24, c4 = (t % 24) * 4;
      const float4 v = *(const float4*)&img_b[(size_t)pos_s[li] * DI + kc * 96 + c4];
      ushort4v h4, l4;
      float fv[4] = {v.x, v.y, v.z, v.w};
#pragma unroll
      for (int q = 0; q < 4; q++) {
        unsigned short hh = f2bf(fv[q]);
        h4[q] = hh;
        l4[q] = f2bf(fv[q] - bf2f(hh));
      }
      *(ushort4v*)&Ah[li][c4] = h4;
      *(ushort4v*)&Al[li][c4] = l4;
    }
    for (int t = tid; t < 48 * 24; t += 256) {
      int j = t / 24, c4 = (t % 24) * 4;
      ushort4v h4 = (ushort4v)0, l4 = (ushort4v)0;
      if (j < 38) {
        int c = (j < 32) ? (j + 6) : (j - 32);
        const float4 v = *(const float4*)&xpw[((size_t)(k * 38 + c)) * DI + kc * 96 + c4];
        float fv[4] = {v.x, v.y, v.z, v.w};
#pragma unroll
        for (int q = 0; q < 4; q++) {
          unsigned short hh = f2bf(fv[q]);
          h4[q] = hh;
          l4[q] = f2bf(fv[q] - bf2f(hh));
        }
      }
      *(ushort4v*)&Wh[j][c4] = h4;
      *(ushort4v*)&Wl[j][c4] = l4;
    }
    __syncthreads();
#pragma unroll
    for (int ks = 0; ks < 3; ks++) {
      short8 ah = *(const short8*)&Ah[wid * 16 + mrow][ks * 32 + quad * 8];
      short8 al = *(const short8*)&Al[wid * 16 + mrow][ks * 32 + quad * 8];
#pragma unroll
      for (int nt = 0; nt < 3; nt++) {
        short8 bh = *(const short8*)&Wh[nt * 16 + mrow][ks * 32 + quad * 8];
        short8 bl = *(const short8*)&Wl[nt * 16 + mrow][ks * 32 + quad * 8];
        acc[nt] = __builtin_amdgcn_mfma_f32_16x16x32_bf16(ah, bh, acc[nt], 0, 0, 0);
        acc[nt] = __builtin_amdgcn_mfma_f32_16x16x32_bf16(al, bh, acc[nt], 0, 0, 0);
        acc[nt] = __builtin_amdgcn_mfma_f32_16x16x32_bf16(ah, bl, acc[nt], 0, 0, 0);
      }
    }
  }
  size_t bkL = (size_t)(b * K_ + k) * L_ + l0;
#pragma unroll
  for (int rg = 0; rg < 4; rg++) {
    int grow = wid * 16 + quad * 4 + rg;
    size_t base = (bkL + grow) * NST;
    BsT[base + mrow] = acc[0][rg];
    CsT[base + mrow] = acc[1][rg];
    if (mrow < R_) dts_g[(bkL + grow) * 8 + mrow] = acc[2][rg];
  }
}

// ---------------- chunked scan pass 1 (register-resident; stores sum_dlt) ----
// grid: ((b*K+k)*NCH + c) ; 192 threads = one per channel d; 16 states/thread
// hend layout: [bk][c][n][d] ; sdl layout: [bk][c][d]
__global__ __launch_bounds__(192) void scan1_kernel(const float* __restrict__ imgT,
    const float* __restrict__ dts_g, const float* __restrict__ BsT,
    const float* __restrict__ a2g, const float* __restrict__ dtw,
    const float* __restrict__ dtb, float* __restrict__ hend,
    float* __restrict__ sdl) {
  __shared__ float bs_s[CL][NST];
  __shared__ float dt_s[CL][8];
  int blk = blockIdx.x;
  int c = blk % NCH;
  int tmp = blk / NCH;
  int k = tmp % K_, b = tmp / K_;
  int l0 = c * CL;
  int d = threadIdx.x;
  const float* img_b = imgT + (size_t)b * L_ * DI;
  {
    const float* Bs_bk = BsT + ((size_t)(b * K_ + k) * L_ + l0) * NST;
    for (int t = d; t < CL * NST; t += 192) bs_s[t >> 4][t & 15] = Bs_bk[t];
    const float* Dt = dts_g + ((size_t)(b * K_ + k) * L_ + l0) * 8;
    for (int t = d; t < CL * 8; t += 192) dt_s[t >> 3][t & 7] = Dt[t];
  }
  float A2[NST];
  {
    const floatx4* ap = (const floatx4*)(a2g + (size_t)(k * DI + d) * NST);
#pragma unroll
    for (int i = 0; i < 4; i++) {
      floatx4 v = ap[i];
      A2[4 * i] = v[0]; A2[4 * i + 1] = v[1]; A2[4 * i + 2] = v[2]; A2[4 * i + 3] = v[3];
    }
  }
  float w6[6], bias;
  {
    const float* wp = dtw + ((size_t)k * DI + d) * R_;
#pragma unroll
    for (int r = 0; r < 6; r++) w6[r] = wp[r];
    bias = dtb[k * DI + d];
  }
  // burst-load all u into registers (32 overlapped loads)
  float u[CL];
#pragma unroll
  for (int q = 0; q < CL; q++)
    u[q] = img_b[(size_t)pos_kl(k, l0 + q) * DI + d];
  __syncthreads();
  // pre-pass: all deltas out of the serial chain
  float dc[CL];
  float sum_dlt = 0.f;
#pragma unroll
  for (int q = 0; q < CL; q++) {
    const floatx4* dp = (const floatx4*)&dt_s[q][0];
    floatx4 d0 = dp[0], d1 = dp[1];
    float s = bias + w6[0] * d0[0] + w6[1] * d0[1] + w6[2] * d0[2]
                   + w6[3] * d0[3] + w6[4] * d1[0] + w6[5] * d1[1];
    dc[q] = softplus_fast(s);
    sum_dlt += dc[q];
  }
  float h[NST];
#pragma unroll
  for (int n = 0; n < NST; n++) h[n] = 0.f;
#pragma unroll
  for (int q = 0; q < CL; q++) {
    float du = dc[q] * u[q];
    floatx4 bsv[4];
    const floatx4* bp = (const floatx4*)&bs_s[q][0];
#pragma unroll
    for (int i = 0; i < 4; i++) bsv[i] = bp[i];
#pragma unroll
    for (int n = 0; n < NST; n++) {
      float dA = exp2_hw(dc[q] * A2[n]);
      h[n] = dA * h[n] + du * bsv[n >> 2][n & 3];
    }
  }
  size_t base = ((size_t)(b * K_ + k) * NCH + c) * (DI * NST) + d;
#pragma unroll
  for (int n = 0; n < NST; n++)
    hend[base + (size_t)n * DI] = h[n];
  sdl[((size_t)(b * K_ + k) * NCH + c) * DI + d] = sum_dlt;
}

// ---------------- carry sweep (aprod recomputed from sum_dlt) ----
// grid: (b*K+k)*DG + part ; thread owns flat (n,d) position
__global__ __launch_bounds__(256) void scan_carry_kernel(float* __restrict__ hend,
    const float* __restrict__ sdl, const float* __restrict__ a2g) {
  constexpr int PF = 8;
  int blk = blockIdx.x;
  int part = blk % DG;
  int bk = blk / DG;
  int k = bk % K_;
  const size_t DNS = (size_t)DI * NST;
  int idx = part * 256 + threadIdx.x;   // 0..3071
  int n = idx / DI;
  int d = idx - n * DI;
  float a2 = a2g[(size_t)(k * DI + d) * NST + n];
  size_t base  = (size_t)bk * NCH * DNS + idx;
  size_t sbase = (size_t)bk * NCH * DI + d;
  float hb[PF], ab[PF];
#pragma unroll
  for (int q = 0; q < PF; q++) {
    hb[q] = hend[base + (size_t)q * DNS];
    ab[q] = exp2_hw(a2 * sdl[sbase + (size_t)q * DI]);
  }
  float carry = 0.f;
  for (int c0 = 0; c0 < NCH; c0 += PF) {
    float hn[PF], an[PF];
    if (c0 + PF < NCH) {
#pragma unroll
      for (int q = 0; q < PF; q++) {
        hn[q] = hend[base + (size_t)(c0 + PF + q) * DNS];
        an[q] = exp2_hw(a2 * sdl[sbase + (size_t)(c0 + PF + q) * DI]);
      }
    } else {
#pragma unroll
      for (int q = 0; q < PF; q++) { hn[q] = 0.f; an[q] = 0.f; }
    }
#pragma unroll
    for (int q = 0; q < PF; q++) {
      hend[base + (size_t)(c0 + q) * DNS] = carry;   // carry entering chunk c0+q
      carry = ab[q] * carry + hb[q];
    }
#pragma unroll
    for (int q = 0; q < PF; q++) { hb[q] = hn[q]; ab[q] = an[q]; }
  }
}

// ---------------- scan pass 2, direction-paired (r5 form, y in LDS) ----
// grid: b*(2*NCH) + pr*NCH + c ; 192 threads = channel d
__global__ __launch_bounds__(192) void scan2_pair_kernel(const float* __restrict__ imgT,
    const float* __restrict__ dts_g, const float* __restrict__ BsT,
    const float* __restrict__ CsT, const float* __restrict__ a2g,
    const float* __restrict__ dtw, const float* __restrict__ dtb,
    const float* __restrict__ Ds, const float* __restrict__ carry_in,
    float* __restrict__ y02, float* __restrict__ y13) {
  __shared__ float bsf[CL][NST], csf[CL][NST], bsr[CL][NST], csr[CL][NST];
  __shared__ float dtf[CL][8], dtr[CL][8];
  __shared__ float y_lds[CL][DI];
  int blk = blockIdx.x;
  int c  = blk % NCH;
  int pr = (blk / NCH) & 1;
  int b  = blk / (2 * NCH);
  int kf = pr, kr = pr + 2;
  int p0 = c * CL;
  int d = threadIdx.x;
  const float* img_b = imgT + (size_t)b * L_ * DI;
  // stage B/C/dts for both directions (reverse rows flipped so index q aligns)
  {
    const float* Bf = BsT + ((size_t)(b * K_ + kf) * L_ + p0) * NST;
    const float* Cf = CsT + ((size_t)(b * K_ + kf) * L_ + p0) * NST;
    for (int t = d; t < CL * NST; t += 192) {
      bsf[t >> 4][t & 15] = Bf[t];
      csf[t >> 4][t & 15] = Cf[t];
    }
    const float* Br = BsT + (size_t)(b * K_ + kr) * L_ * NST;
    const float* Cr = CsT + (size_t)(b * K_ + kr) * L_ * NST;
    for (int t = d; t < CL * NST; t += 192) {
      int q = t >> 4, n = t & 15;
      size_t sr = (size_t)(L_ - 1 - p0 - q) * NST + n;
      bsr[q][n] = Br[sr];
      csr[q][n] = Cr[sr];
    }
    const float* Df = dts_g + ((size_t)(b * K_ + kf) * L_ + p0) * 8;
    for (int t = d; t < CL * 8; t += 192) dtf[t >> 3][t & 7] = Df[t];
    const float* Dr = dts_g + (size_t)(b * K_ + kr) * L_ * 8;
    for (int t = d; t < CL * 8; t += 192) {
      int q = t >> 3, r = t & 7;
      dtr[q][r] = Dr[(size_t)(L_ - 1 - p0 - q) * 8 + r];
    }
  }
  // burst-load u (shared by both directions)
  float u[CL];
#pragma unroll
  for (int q = 0; q < CL; q++)
    u[q] = img_b[(size_t)pos_pair(pr, p0 + q) * DI + d];
  float dsum = 0.f;
  if (pr == 0) dsum = Ds[d] + Ds[DI + d] + Ds[2 * DI + d] + Ds[3 * DI + d];
  __syncthreads();
  float A2[NST], h[NST], w6[6], bias, dc[CL];
  // ---- loop 1: forward direction kf, positions ascending ----
  {
    const floatx4* ap = (const floatx4*)(a2g + (size_t)(kf * DI + d) * NST);
#pragma unroll
    for (int i = 0; i < 4; i++) {
      floatx4 v = ap[i];
      A2[4 * i] = v[0]; A2[4 * i + 1] = v[1]; A2[4 * i + 2] = v[2]; A2[4 * i + 3] = v[3];
    }
    size_t cb = ((size_t)(b * K_ + kf) * NCH + c) * (DI * NST) + d;
#pragma unroll
    for (int n = 0; n < NST; n++) h[n] = carry_in[cb + (size_t)n * DI];
    const float* wp = dtw + ((size_t)kf * DI + d) * R_;
#pragma unroll
    for (int r = 0; r < 6; r++) w6[r] = wp[r];
    bias = dtb[kf * DI + d];
  }
#pragma unroll
  for (int q = 0; q < CL; q++) {
    const floatx4* dp = (const floatx4*)&dtf[q][0];
    floatx4 d0 = dp[0], d1 = dp[1];
    float s = bias + w6[0] * d0[0] + w6[1] * d0[1] + w6[2] * d0[2]
                   + w6[3] * d0[3] + w6[4] * d1[0] + w6[5] * d1[1];
    dc[q] = softplus_fast(s);
  }
#pragma unroll
  for (int q = 0; q < CL; q++) {
    float du = dc[q] * u[q];
    floatx4 bsv[4], csv[4];
    const floatx4* bp = (const floatx4*)&bsf[q][0];
    const floatx4* cp = (const floatx4*)&csf[q][0];
#pragma unroll
    for (int i = 0; i < 4; i++) { bsv[i] = bp[i]; csv[i] = cp[i]; }
    float yq = dsum * u[q];
#pragma unroll
    for (int n = 0; n < NST; n++) {
      float dA = exp2_hw(dc[q] * A2[n]);
      h[n] = dA * h[n] + du * bsv[n >> 2][n & 3];
      yq += h[n] * csv[n >> 2][n & 3];
    }
    y_lds[q][d] = yq;   // own-thread slot; no barrier needed
  }
  // ---- loop 2: reverse direction kr, positions descending (steps ascend) ----
  {
    const floatx4* ap = (const floatx4*)(a2g + (size_t)(kr * DI + d) * NST);
#pragma unroll
    for (int i = 0; i < 4; i++) {
      floatx4 v = ap[i];
      A2[4 * i] = v[0]; A2[4 * i + 1] = v[1]; A2[4 * i + 2] = v[2]; A2[4 * i + 3] = v[3];
    }
    size_t cb = ((size_t)(b * K_ + kr) * NCH + (NCH - 1 - c)) * (DI * NST) + d;
#pragma unroll
    for (int n = 0; n < NST; n++) h[n] = carry_in[cb + (size_t)n * DI];
    const float* wp = dtw + ((size_t)kr * DI + d) * R_;
#pragma unroll
    for (int r = 0; r < 6; r++) w6[r] = wp[r];
    bias = dtb[kr * DI + d];
  }
#pragma unroll
  for (int q = 0; q < CL; q++) {
    const floatx4* dp = (const floatx4*)&dtr[q][0];
    floatx4 d0 = dp[0], d1 = dp[1];
    float s = bias + w6[0] * d0[0] + w6[1] * d0[1] + w6[2] * d0[2]
                   + w6[3] * d0[3] + w6[4] * d1[0] + w6[5] * d1[1];
    dc[q] = softplus_fast(s);
  }
  float* yout = (pr == 0) ? y02 : y13;
#pragma unroll
  for (int qq = 0; qq < CL; qq++) {
    int q = CL - 1 - qq;
    float du = dc[q] * u[q];
    floatx4 bsv[4], csv[4];
    const floatx4* bp = (const floatx4*)&bsr[q][0];
    const floatx4* cp = (const floatx4*)&csr[q][0];
#pragma unroll
    for (int i = 0; i < 4; i++) { bsv[i] = bp[i]; csv[i] = cp[i]; }
    float yq = y_lds[q][d];
#pragma unroll
    for (int n = 0; n < NST; n++) {
      float dA = exp2_hw(dc[q] * A2[n]);
      h[n] = dA * h[n] + du * bsv[n >> 2][n & 3];
      yq += h[n] * csv[n >> 2][n & 3];
    }
    yout[((size_t)b * L_ + pos_pair(pr, p0 + q)) * DI + d] = yq;
  }
}

// ---------------- LN over Di=192 of (y02+y13) + multiply by silu(z) ----------------
__global__ __launch_bounds__(256) void ln_mulz_kernel(const float* __restrict__ y02,
    const float* __restrict__ y13, const float* __restrict__ g,
    const float* __restrict__ bb, float* __restrict__ z) {
  int wave = blockIdx.x * 4 + (threadIdx.x >> 6);
  int lane = threadIdx.x & 63;
  const float* rp = y02 + (size_t)wave * DI;
  const float* rq = y13 + (size_t)wave * DI;
  float v0 = rp[lane]       + rq[lane];
  float v1 = rp[lane + 64]  + rq[lane + 64];
  float v2 = rp[lane + 128] + rq[lane + 128];
  float s  = wave_sum64(v0 + v1 + v2);
  float s2 = wave_sum64(v0 * v0 + v1 * v1 + v2 * v2);
  float mean = s * (1.f / DI);
  float var  = s2 * (1.f / DI) - mean * mean;
  float inv  = rsqrtf(var + 1e-5f);
  float* zp = z + (size_t)wave * DI;
  float vv[3] = {v0, v1, v2};
#pragma unroll
  for (int q = 0; q < 3; q++) {
    int c = lane + 64 * q;
    float zv = zp[c];
    zp[c] = ((vv[q] - mean) * inv * g[c] + bb[c]) * silu_f(zv);
  }
}

// ---------------- out_proj via bf16 hi/lo MFMA + residual add ----------------
// x_res[M,96] = yz[M,192] @ wo[96,192]^T + x ; 64-row tile, 256 threads (4 waves)
__global__ __launch_bounds__(256) void outproj_mfma_kernel(const float* __restrict__ yz,
    const unsigned short* __restrict__ wo, const float* __restrict__ x,
    float* __restrict__ x_res) {
  __shared__ __align__(16) unsigned short Wh[96][104];
  __shared__ __align__(16) unsigned short Wl[96][104];
  int row0 = blockIdx.x * 64;
  int tid = threadIdx.x;
  int wv = tid >> 6, lane = tid & 63, mrow = lane & 15, quad = lane >> 4;

  floatx4 acc[6];
#pragma unroll
  for (int q = 0; q < 6; q++) acc[q] = (floatx4)(0.f);

  const float* yr = yz + (size_t)(row0 + wv * 16 + mrow) * DI;
  for (int kc = 0; kc < 2; kc++) {     // 2 K-chunks of 96
    if (kc) __syncthreads();
    // stage W chunk: rows j=0..95, cols kc*96..+95 (hi at 0, lo at +18432)
    for (int t = tid; t < 96 * 12; t += 256) {
      int j = t / 12, u = t % 12;
      *(short8*)&Wh[j][u * 8] = *(const short8*)&wo[(size_t)j * DI + kc * 96 + u * 8];
      *(short8*)&Wl[j][u * 8] = *(const short8*)&wo[18432 + (size_t)j * DI + kc * 96 + u * 8];
    }
    __syncthreads();
    // A-fragments from global per ks
#pragma unroll
    for (int ks = 0; ks < 3; ks++) {
      float4 va = *(const float4*)&yr[kc * 96 + ks * 32 + quad * 8];
      float4 vb = *(const float4*)&yr[kc * 96 + ks * 32 + quad * 8 + 4];
      float f[8] = {va.x, va.y, va.z, va.w, vb.x, vb.y, vb.z, vb.w};
      short8 ah, al;
#pragma unroll
      for (int q = 0; q < 8; q++) {
        unsigned short hv = f2bf(f[q]);
        ah[q] = (short)hv;
        al[q] = (short)f2bf(f[q] - bf2f(hv));
      }
#pragma unroll
      for (int nt = 0; nt < 6; nt++) {
        short8 bh = *(const short8*)&Wh[nt * 16 + mrow][ks * 32 + quad * 8];
        short8 bl = *(const short8*)&Wl[nt * 16 + mrow][ks * 32 + quad * 8];
        acc[nt] = __builtin_amdgcn_mfma_f32_16x16x32_bf16(ah, bh, acc[nt], 0, 0, 0);
        acc[nt] = __builtin_amdgcn_mfma_f32_16x16x32_bf16(al, bh, acc[nt], 0, 0, 0);
        acc[nt] = __builtin_amdgcn_mfma_f32_16x16x32_bf16(ah, bl, acc[nt], 0, 0, 0);
      }
    }
  }
  // epilogue: col = nt*16 + mrow, row = row0 + wv*16 + quad*4 + rg ; + residual
#pragma unroll
  for (int nt = 0; nt < 6; nt++) {
    int j = nt * 16 + mrow;
#pragma unroll
    for (int rg = 0; rg < 4; rg++) {
      int row = row0 + wv * 16 + quad * 4 + rg;
      x_res[(size_t)row * C_ + j] = x[(size_t)row * C_ + j] + acc[nt][rg];
    }
  }
}

// ---------------- weight prep: pack [bw|sw] per layer into bf16 Wcat[3][96][864] ----------------
__global__ __launch_bounds__(256) void prepw_kernel(const float* __restrict__ bw1,
    const float* __restrict__ sw1, const float* __restrict__ bw2,
    const float* __restrict__ sw2, const float* __restrict__ bw3,
    const float* __restrict__ sw3, unsigned short* __restrict__ wcat) {
  int idx = blockIdx.x * 256 + threadIdx.x;
  if (idx >= 3 * KLAY) return;
  int layer = idx / KLAY, rem = idx % KLAY;
  int j = rem / KANK, k = rem % KANK;
  const float* bw = (layer == 0) ? bw1 : (layer == 1) ? bw2 : bw3;
  const float* sw = (layer == 0) ? sw1 : (layer == 1) ? sw2 : sw3;
  float v = (k < C_) ? bw[j * C_ + k] : sw[j * 768 + (k - C_)];
  wcat[idx] = f2bf(v);
}

// ---------------- KAN linear via bf16 MFMA ----------------
// 32-row tile, 256 threads (4 waves): wave (rh,ch) owns rows rh*16.. and cols ch*48..
__global__ __launch_bounds__(256) void kan_mfma_kernel(const float* __restrict__ in,
    const unsigned short* __restrict__ wl, float* __restrict__ out) {
  __shared__ __align__(16) float x_s[32][100];
  __shared__ __align__(16) unsigned short A_s[32][104];
  __shared__ __align__(16) unsigned short W_s[96][104];
  int row0 = blockIdx.x * 32;
  int tid = threadIdx.x;
  for (int t = tid; t < 32 * 24; t += 256) {
    int r = t / 24, c4 = (t % 24) * 4;
    *(float4*)&x_s[r][c4] = *(const float4*)&in[(size_t)(row0 + r) * C_ + c4];
  }
  floatx4 acc[3];
#pragma unroll
  for (int q = 0; q < 3; q++) acc[q] = (floatx4)(0.f);
  int wv = tid >> 6;
  int rh = wv >> 1, ch = wv & 1;
  int lane = tid & 63;
  int mrow = lane & 15, quad = lane >> 4;
  __syncthreads();
  for (int ci = 0; ci < 9; ci++) {
    if (ci) __syncthreads();
    for (int t = tid; t < 96 * 12; t += 256) {
      int j = t / 12, u = t % 12;
      *(short8*)&W_s[j][u * 8] =
          *(const short8*)&wl[(size_t)j * KANK + ci * 96 + u * 8];
    }
    if (ci == 0) {
      for (int t = tid; t < 32 * 48; t += 256) {
        int r = t / 48, k2 = (t % 48) * 2;
        unsigned v = (unsigned)f2bf(silu_f(x_s[r][k2])) |
                     ((unsigned)f2bf(silu_f(x_s[r][k2 + 1])) << 16);
        *(unsigned*)&A_s[r][k2] = v;
      }
    } else {
      int c0 = (ci - 1) * 12;
      for (int t = tid; t < 32 * 12; t += 256) {
        int r = t & 31, cl = t >> 5;   // cl 0..11
        float x = x_s[r][c0 + cl];
        float bb[11];
        spline8(x, bb);
        short8 av;
#pragma unroll
        for (int q = 0; q < 8; q++) av[q] = (short)f2bf(bb[q]);
        *(short8*)&A_s[r][cl * 8] = av;
      }
    }
    __syncthreads();
#pragma unroll
    for (int ks = 0; ks < 3; ks++) {
      short8 a = *(const short8*)&A_s[rh * 16 + mrow][ks * 32 + quad * 8];
#pragma unroll
      for (int ct = 0; ct < 3; ct++) {
        short8 b = *(const short8*)&W_s[ch * 48 + ct * 16 + mrow][ks * 32 + quad * 8];
        acc[ct] = __builtin_amdgcn_mfma_f32_16x16x32_bf16(a, b, acc[ct], 0, 0, 0);
      }
    }
  }
#pragma unroll
  for (int ct = 0; ct < 3; ct++)
#pragma unroll
    for (int rg = 0; rg < 4; rg++) {
      int row = row0 + rh * 16 + quad * 4 + rg;
      out[(size_t)row * C_ + ch * 48 + ct * 16 + mrow] = acc[ct][rg];
    }
}

// ---------------- depthwise 3x3 + BN-ish scale + ReLU (+ optional residual) ----------------
// 4 pixels per block: threads 0..95 -> pixels (p0,p0+1), 96..191 -> (p0+2,p0+3)
__global__ __launch_bounds__(192) void dwbn_kernel(const float* __restrict__ t,
    const float* __restrict__ w, const float* __restrict__ bias,
    const float* __restrict__ gamma, const float* __restrict__ beta,
    const float* __restrict__ addres, float* __restrict__ out) {
  int tid = threadIdx.x;
  int half = (tid >= 96) ? 1 : 0;
  int c = tid - half * 96;
  int p0 = blockIdx.x * 4 + half * 2;
  int b = p0 >> 12;
  int ij = p0 & 4095;
  int i = ij >> 6, j0 = ij & 63;   // j0 even, j0+1 <= 63
  float v[3][4];
#pragma unroll
  for (int r = 0; r < 3; r++) {
    int ii = i - 1 + r;
    bool rok = (ii >= 0 && ii < H_);
#pragma unroll
    for (int cc = 0; cc < 4; cc++) {
      int jj = j0 - 1 + cc;
      v[r][cc] = (rok && jj >= 0 && jj < W_)
                     ? t[((size_t)b * L_ + ii * W_ + jj) * C_ + c] : 0.f;
    }
  }
  const float* wc = w + c * 9;
  float wv[9];
#pragma unroll
  for (int q = 0; q < 9; q++) wv[q] = wc[q];
  float a0 = bias[c], a1 = a0;
#pragma unroll
  for (int r = 0; r < 3; r++) {
#pragma unroll
    for (int tt = 0; tt < 3; tt++) {
      a0 += v[r][tt]     * wv[r * 3 + tt];
      a1 += v[r][tt + 1] * wv[r * 3 + tt];
    }
  }
  float gsc = gamma[c] * rsqrtf(1.f + 1e-5f);
  float bt = beta[c];
  float o0 = fmaxf(a0 * gsc + bt, 0.f);
  float o1 = fmaxf(a1 * gsc + bt, 0.f);
  if (addres != nullptr) {
    o0 += addres[(size_t)p0 * C_ + c];
    o1 += addres[(size_t)(p0 + 1) * C_ + c];
  }
  out[(size_t)p0 * C_ + c]       = o0;
  out[(size_t)(p0 + 1) * C_ + c] = o1;
}

// ---------------- host launcher ----------------
extern "C" void kernel_launch(void* const* d_in, const int* in_sizes, int n_in,
                              void* d_out, int out_size, void* d_ws, size_t ws_size,
                              hipStream_t stream) {
  const float* x         = (const float*)d_in[0];
  const float* norm1_g   = (const float*)d_in[3];
  const float* norm1_b   = (const float*)d_in[4];
  const float* in_proj_w = (const float*)d_in[5];
  const float* conv_w    = (const float*)d_in[6];
  const float* conv_b    = (const float*)d_in[7];
  const float* x_proj_w  = (const float*)d_in[8];
  const float* dt_w      = (const float*)d_in[9];
  const float* dt_b      = (const float*)d_in[10];
  const float* A_logs    = (const float*)d_in[11];
  const float* Ds        = (const float*)d_in[12];
  const float* out_ng    = (const float*)d_in[13];
  const float* out_nb    = (const float*)d_in[14];
  const float* out_proj_w= (const float*)d_in[15];
  const float* norm2_g   = (const float*)d_in[16];
  const float* norm2_b   = (const float*)d_in[17];
  const float* fc1_bw    = (const float*)d_in[18];
  const float* fc1_sw    = (const float*)d_in[19];
  const float* fc2_bw    = (const float*)d_in[20];
  const float* fc2_sw    = (const float*)d_in[21];
  const float* fc3_bw    = (const float*)d_in[22];
  const float* fc3_sw    = (const float*)d_in[23];
  const float* dw1_w     = (const float*)d_in[24];
  const float* dw1_b     = (const float*)d_in[25];
  const float* dw1_g     = (const float*)d_in[26];
  const float* dw1_be    = (const float*)d_in[27];
  const float* dw2_w     = (const float*)d_in[28];
  const float* dw2_b     = (const float*)d_in[29];
  const float* dw2_g     = (const float*)d_in[30];
  const float* dw2_be    = (const float*)d_in[31];
  const float* dw3_w     = (const float*)d_in[32];
  const float* dw3_b     = (const float*)d_in[33];
  const float* dw3_g     = (const float*)d_in[34];
  const float* dw3_be    = (const float*)d_in[35];

  float* ws = (float*)d_ws;
  float* h_buf   = ws;                       // M*96
  float* xin_buf = h_buf + (size_t)M_ * C_;  // M*192 (reused as y13 after conv)
  float* z_buf   = xin_buf + (size_t)M_ * DI;
  float* imgT    = z_buf + (size_t)M_ * DI;
  float* BsT     = imgT + (size_t)M_ * DI;                 // B*K*L*16
  float* CsT     = BsT + (size_t)B_ * K_ * L_ * NST;
  float* y_pre   = CsT + (size_t)B_ * K_ * L_ * NST;       // M*192 (= y02)
  float* x_res   = y_pre + (size_t)M_ * DI;                // M*96
  float* t_a     = x_res + (size_t)M_ * C_;                // M*96
  float* t_b     = t_a + (size_t)M_ * C_;                  // M*96
  float* hend    = t_b + (size_t)M_ * C_;                  // B*K*NCH*DI*NST
  float* sdl_buf = hend + (size_t)B_ * K_ * NCH * DI * NST; // B*K*NCH*DI (1.5MB)
  float* a2_buf  = sdl_buf + (size_t)B_ * K_ * NCH * DI;    // K*DI*NST = 12288
  // aliases (lifetimes disjoint):
  float* dts_g   = t_a;                        // B*K*L*8 floats; t_a used only post-scan
  unsigned short* wio  = (unsigned short*)t_b; // in_proj hi/lo bf16; t_b used only post-scan
  unsigned short* wo_p = wio + 2 * 36864;      // out_proj hi/lo bf16 (t_b slack, 74KB)
  float* y13     = xin_buf;                    // xin dead after conv
  unsigned short* wcat = (unsigned short*)BsT; // bf16 KAN weights; BsT dead after scan2

  // 1. LN1
  ln96_kernel<<<M_ / 4, 256, 0, stream>>>(x, norm1_g, norm1_b, h_buf);
  // 2. in_proj -> xin, z  (bf16 hi/lo MFMA)
  prep_inproj_kernel<<<144, 256, 0, stream>>>(in_proj_w, wio);
  prep_outproj_kernel<<<72, 256, 0, stream>>>(out_proj_w, wo_p);
  prep_a2_kernel<<<48, 256, 0, stream>>>(A_logs, a2_buf);
  gemm_in_mfma_kernel<<<(M_ / 64) * 2, 256, 0, stream>>>(h_buf, wio, xin_buf, z_buf);
  // 3. dwconv + silu -> imgT (NHWC), 2 px/block
  conv_silu_kernel<<<M_ / 2, 192, 0, stream>>>(xin_buf, conv_w, conv_b, imgT);
  // 4. x_dbl projections (bf16x2 MFMA) -> BsT, CsT, dts
  xdbl_mfma_kernel<<<B_ * K_ * (L_ / 64), 256, 0, stream>>>(imgT, x_proj_w, dts_g,
                                                            BsT, CsT);
  // 5. chunked selective scan
  scan1_kernel<<<B_ * K_ * NCH, 192, 0, stream>>>(imgT, dts_g, BsT, a2_buf,
                                                  dt_w, dt_b, hend, sdl_buf);
  scan_carry_kernel<<<B_ * K_ * DG, 256, 0, stream>>>(hend, sdl_buf, a2_buf);
  scan2_pair_kernel<<<B_ * 2 * NCH, 192, 0, stream>>>(imgT, dts_g, BsT, CsT, a2_buf,
                                                      dt_w, dt_b, Ds, hend,
                                                      y_pre, y13);
  // 5b. pack KAN weights to bf16 (BsT region is dead from here on)
  prepw_kernel<<<(3 * KLAY + 255) / 256, 256, 0, stream>>>(fc1_bw, fc1_sw, fc2_bw,
                                                           fc2_sw, fc3_bw, fc3_sw, wcat);
  // 6. out-norm LN of (y02+y13) + silu(z) gate (in-place into z)
  ln_mulz_kernel<<<M_ / 4, 256, 0, stream>>>(y_pre, y13, out_ng, out_nb, z_buf);
  // 7. out_proj + residual (bf16 hi/lo MFMA)
  outproj_mfma_kernel<<<M_ / 64, 256, 0, stream>>>(z_buf, wo_p, x, x_res);
  // 8. LN2
  ln96_kernel<<<M_ / 4, 256, 0, stream>>>(x_res, norm2_g, norm2_b, h_buf);
  // 9. KAN (bf16 MFMA) / dw-bn-relu chain (dwbn: 4 px/block)
  kan_mfma_kernel<<<M_ / 32, 256, 0, stream>>>(h_buf, wcat, t_a);
  dwbn_kernel<<<M_ / 4, 192, 0, stream>>>(t_a, dw1_w, dw1_b, dw1_g, dw1_be, nullptr, t_b);
  kan_mfma_kernel<<<M_ / 32, 256, 0, stream>>>(t_b, wcat + KLAY, t_a);
  dwbn_kernel<<<M_ / 4, 192, 0, stream>>>(t_a, dw2_w, dw2_b, dw2_g, dw2_be, nullptr, t_b);
  kan_mfma_kernel<<<M_ / 32, 256, 0, stream>>>(t_b, wcat + 2 * KLAY, t_a);
  dwbn_kernel<<<M_ / 4, 192, 0, stream>>>(t_a, dw3_w, dw3_b, dw3_g, dw3_be, x_res, (float*)d_out);
}